// Round 9
// baseline (303.579 us; speedup 1.0000x reference)
//
#include <hip/hip_runtime.h>
#include <cstdint>

typedef unsigned short u16;
typedef unsigned int u32;
typedef u16 u16x8 __attribute__((ext_vector_type(8)));
typedef u16 u16x4 __attribute__((ext_vector_type(4)));
typedef short short8 __attribute__((ext_vector_type(8)));
typedef float f32x4 __attribute__((ext_vector_type(4)));

__device__ __forceinline__ float bf2f(u16 u){ return __uint_as_float(((u32)u)<<16); }
__device__ __forceinline__ u16 f2bf(float f){
  u32 x = __float_as_uint(f);
  return (u16)((x + 0x7fffu + ((x>>16)&1u)) >> 16);
}
__device__ __forceinline__ float siluf(float v){ return v/(1.f + __expf(-v)); }

// B=8, L=4096, C=256, D_INNER=512, CONV_DIM=544, NH=8, HD=64, DS=16, chunk Lc=64
// zxT layout: [1056 cols][32768 m] bf16. cols 0..511 = z; 512..1055 = xBC.
//   xT view = zxT + 512*32768: x-part rows 0..511, B rows 512..527, C rows 528..543.

// ---------------- K0: weights -> bf16 ----------------
__global__ __launch_bounds__(256) void k0_wprep(const float* __restrict__ w1,
                                                const float* __restrict__ w2,
                                                u16* __restrict__ w1b, u16* __restrict__ w2b){
  u32 idx = blockIdx.x*256u + threadIdx.x;
  const u32 W1N = 1152u*256u;
  const u32 W2N = 256u*512u;
  if (idx < W1N){
    u32 n = idx >> 8;
    w1b[idx] = (n < 1064u) ? f2bf(w1[idx]) : (u16)0;
  } else if (idx < W1N + W2N){
    u32 j = idx - W1N;
    w2b[j] = f2bf(w2[j]);
  }
}

// ---------------- K1: transpose + LayerNorm + dt(f32) ----------------
__global__ __launch_bounds__(256) void k1_ln(const float* __restrict__ x,
                                             const float* __restrict__ ln_w, const float* __restrict__ ln_b,
                                             const float* __restrict__ w1,
                                             u16* __restrict__ xnb, float* __restrict__ dtr){
  __shared__ float tile[256][33];
  __shared__ float mu_s[32], rs_s[32];
  const int b  = blockIdx.y;
  const int l0 = blockIdx.x*32;
  const int tid = threadIdx.x;
  const size_t xbase = (size_t)b*256*4096;
  const int cl = tid>>5;
  const int ll = tid&31;
  for (int cc=0; cc<256; cc+=8){
    int c = cc + cl;
    tile[c][ll] = x[xbase + (size_t)c*4096 + l0 + ll];
  }
  __syncthreads();
  const int lane = tid&63, wave = tid>>6;
  const int lidx = wave*8 + (lane&7);
  const int c0 = (lane>>3)*32;
  float s=0.f, ss=0.f;
  for (int c=c0; c<c0+32; ++c){ float v = tile[c][lidx]; s += v; ss += v*v; }
  for (int off=8; off<64; off<<=1){ s += __shfl_xor(s, off); ss += __shfl_xor(ss, off); }
  float mu = s*(1.f/256.f);
  float var = ss*(1.f/256.f) - mu*mu;
  float rs = rsqrtf(var + 1e-5f);
  if ((lane>>3)==0){ mu_s[lidx]=mu; rs_s[lidx]=rs; }
  __syncthreads();
  {
    const int c = tid;
    const float lw = ln_w[c], lb = ln_b[c];
    for (int l=0; l<32; ++l){
      float v = (tile[c][l]-mu_s[l])*rs_s[l]*lw + lb;
      xnb[((size_t)b*4096 + l0 + l)*256 + c] = f2bf(v);
    }
  }
  {
    const int r = tid>>3, j = tid&7;
    const float* wr = w1 + (size_t)(1056+j)*256;
    const float mur = mu_s[r], rsr = rs_s[r];
    float acc = 0.f;
    for (int c=0; c<256; ++c){
      float v = (tile[c][r]-mur)*rsr*ln_w[c] + ln_b[c];
      acc += v*wr[c];
    }
    dtr[((size_t)b*4096 + l0 + r)*8 + j] = acc;
  }
}

// ---------------- K2: GEMM1 128x128, XCD-swizzled, all outputs transposed ----------------
__global__ __launch_bounds__(256) void k2_gemm1(const u16* __restrict__ A, const u16* __restrict__ W,
                                                u16* __restrict__ zxT){
  __shared__ u16 sA[128*40];
  __shared__ u16 sW[128*40];
  const int tid = threadIdx.x, lane = tid&63, wave = tid>>6;
  // bijective decode: all 9 n-tiles of an m-panel share dispatch-slot%8 (same XCD)
  const int s = blockIdx.x;
  const int kx = s & 7;
  const int idx = s >> 3;          // 0..287
  const int xn = idx % 9;
  const int ym = (idx/9)*8 + kx;   // 0..255
  const size_t m0 = (size_t)ym*128;
  const int n0 = xn*128;
  const int wm = (wave>>1)*64, wn = (wave&1)*64;
  f32x4 acc[4][4] = {};
  const int fr = lane&15, kc = (lane>>4)*8;
  for (int k0=0; k0<256; k0+=32){
    #pragma unroll
    for (int j=0; j<2; ++j){
      int ch = j*256 + tid, r = ch>>2, co = (ch&3)*8;
      *(u16x8*)&sA[r*40+co] = *(const u16x8*)&A[(m0+r)*256 + k0 + co];
      *(u16x8*)&sW[r*40+co] = *(const u16x8*)&W[(size_t)(n0+r)*256 + k0 + co];
    }
    __syncthreads();
    short8 af[4], bf4[4];
    #pragma unroll
    for (int fm=0; fm<4; ++fm) af[fm]  = *(short8*)&sA[(wm+fm*16+fr)*40 + kc];
    #pragma unroll
    for (int fn=0; fn<4; ++fn) bf4[fn] = *(short8*)&sW[(wn+fn*16+fr)*40 + kc];
    #pragma unroll
    for (int fm=0; fm<4; ++fm)
      #pragma unroll
      for (int fn=0; fn<4; ++fn)
        acc[fm][fn] = __builtin_amdgcn_mfma_f32_16x16x32_bf16(af[fm],bf4[fn],acc[fm][fn],0,0,0);
    __syncthreads();
  }
  #pragma unroll
  for (int fm=0; fm<4; ++fm)
    #pragma unroll
    for (int fn=0; fn<4; ++fn){
      int rb = wm + fm*16 + ((lane>>4)<<2);
      int col = n0 + wn + fn*16 + (lane&15);
      size_t m = m0 + rb;
      if (col < 1056){
        u16x4 o;
        #pragma unroll
        for (int i=0; i<4; ++i) o[i] = f2bf(acc[fm][fn][i]);
        *(u16x4*)&zxT[(size_t)col*32768 + m] = o;
      }
    }
}

// ---------------- kU: chunk-end states via MFMA ----------------
__global__ __launch_bounds__(256,3) void kU(const u16* __restrict__ xT, const float* __restrict__ dtr,
                                          const float* __restrict__ conv_w, const float* __restrict__ conv_b,
                                          const float* __restrict__ dt_bias, const float* __restrict__ A_log,
                                          float* __restrict__ hend, float* __restrict__ aprod){
  __shared__ char lds[44816];
  float* rawB = (float*)(lds + 0);        // [67][17] f32
  u16*   BcT  = (u16*)(lds + 4560);       // [16][72] bf16
  float* wl   = (float*)(lds + 6864);     // [4][64] f32
  const int ck = blockIdx.x, b = blockIdx.y, half = blockIdx.z;
  const int tid = threadIdx.x, lane = tid&63, hh = tid>>6;
  const int h = half*4 + hh;
  const int m0 = b*4096 + ck*64;
  u16* XW = (u16*)(lds + 7888 + hh*9232); // [64][72] per head
  // (a) raw B staging (coalesced along m) + dt cumsum
  for (int i=tid; i<16*72; i+=256){
    int n = i/72, r = i - n*72;
    if (r < 67){
      int l = ck*64 - 3 + r;
      rawB[r*17+n] = (l>=0) ? bf2f(xT[(size_t)(512+n)*32768 + (size_t)b*4096 + l]) : 0.f;
    }
  }
  {
    int t = lane;
    float dr = dtr[(size_t)(m0+t)*8 + h] + dt_bias[h];
    float dt = (dr > 20.f) ? dr : log1pf(__expf(dr));
    float Ah = -__expf(A_log[h]);
    float v = dt*Ah;
    #pragma unroll
    for (int off=1; off<64; off<<=1){ float p = __shfl_up(v, off); if (lane >= off) v += p; }
    float scT = __shfl(v, 63);
    wl[hh*64 + t] = dt * __expf(scT - v);
    if (lane==0) aprod[(b*8+h)*64 + ck] = __expf(scT);
  }
  __syncthreads();
  // (b) BcT build + weighted X staging (vector loads along t)
  for (int i=tid; i<16*64; i+=256){
    int n = i>>6, s2 = i&63;
    int c = 512+n;
    float a = conv_b[c] + conv_w[c*4+0]*rawB[s2*17+n] + conv_w[c*4+1]*rawB[(s2+1)*17+n]
            + conv_w[c*4+2]*rawB[(s2+2)*17+n] + conv_w[c*4+3]*rawB[(s2+3)*17+n];
    BcT[n*72 + s2] = f2bf(siluf(a));
  }
  {
    const int c = h*64 + lane;
    const float w0=conv_w[c*4], w1=conv_w[c*4+1], w2=conv_w[c*4+2], w3=conv_w[c*4+3];
    const float cb = conv_b[c];
    const u16* xcol = xT + (size_t)c*32768 + (size_t)b*4096 + ck*64;
    u16x8 wv[9]; u16x8 zer = {};
    wv[0] = (ck>0) ? *(const u16x8*)(xcol - 8) : zer;
    #pragma unroll
    for (int j=0;j<8;++j) wv[j+1] = *(const u16x8*)(xcol + j*8);
    #pragma unroll
    for (int t8=0; t8<8; ++t8){
      u16x8 o;
      #pragma unroll
      for (int j=0;j<8;++j){
        const int t = t8*8+j;
        float x0 = bf2f(wv[(t+5)>>3][(t+5)&7]);
        float x1 = bf2f(wv[(t+6)>>3][(t+6)&7]);
        float x2 = bf2f(wv[(t+7)>>3][(t+7)&7]);
        float x3 = bf2f(wv[(t+8)>>3][(t+8)&7]);
        o[j] = f2bf(siluf(cb + w0*x0 + w1*x1 + w2*x2 + w3*x3) * wl[hh*64 + t]);
      }
      *(u16x8*)&XW[lane*72 + t8*8] = o;
    }
  }
  __syncthreads();
  // (c) U = (w∘X)^T @ Bc
  const int fr = lane&15, g = lane>>4;
  f32x4 acc4[4] = {};
  #pragma unroll
  for (int ks=0; ks<2; ++ks){
    short8 bfr = *(short8*)&BcT[fr*72 + ks*32 + g*8];
    #pragma unroll
    for (int ti=0; ti<4; ++ti){
      short8 afr = *(short8*)&XW[(ti*16+fr)*72 + ks*32 + g*8];
      acc4[ti] = __builtin_amdgcn_mfma_f32_16x16x32_bf16(afr, bfr, acc4[ti], 0,0,0);
    }
  }
  size_t hb = ((size_t)((b*8+h)*64 + ck))*64;
  #pragma unroll
  for (int ti=0; ti<4; ++ti)
    #pragma unroll
    for (int i=0; i<4; ++i){
      int p = ti*16 + g*4 + i;
      hend[(hb + p)*16 + fr] = acc4[ti][i];
    }
}

// ---------------- K5: inter-chunk recurrence (4 waves, n-split) ----------------
__global__ __launch_bounds__(256) void k5_phase2(const float* __restrict__ hend, const float* __restrict__ aprod,
                                                 float* __restrict__ hs){
  const int bh = blockIdx.x;
  const int w = threadIdx.x>>6, lane = threadIdx.x&63;
  const int n0 = w*4;
  f32x4 hr = {0.f,0.f,0.f,0.f};
  for (int ck=0; ck<64; ++ck){
    size_t base = (((size_t)bh*64 + ck)*64 + lane)*16 + n0;
    float a = aprod[bh*64 + ck];
    *(f32x4*)&hs[base] = hr;
    f32x4 he = *(const f32x4*)&hend[base];
    hr = a*hr + he;
  }
}

// ---------------- kYR: chunk outputs via MFMA + fused gate/RMSNorm ----------------
__global__ __launch_bounds__(512) void kYR(const u16* __restrict__ xT, const u16* __restrict__ zxT,
                                           const float* __restrict__ dtr,
                                           const float* __restrict__ conv_w, const float* __restrict__ conv_b,
                                           const float* __restrict__ dt_bias, const float* __restrict__ A_log,
                                           const float* __restrict__ Dp, const float* __restrict__ rms_w,
                                           const float* __restrict__ hs, u16* __restrict__ ynb){
  __shared__ char lds[91520];
  u16*   G     = (u16*)(lds + 0);       // [64][72] bf16 (union rawBC)
  float* rawBC = (float*)(lds + 0);     // [67][33] f32
  u16*   Cc    = (u16*)(lds + 9216);    // [64][16] bf16 (unpadded)
  u16*   Bc    = (u16*)(lds + 11264);   // [64][16]
  float* scs   = (float*)(lds + 13312); // [8][68]
  float* dth   = (float*)(lds + 15488); // [8][68]
  const int ck = blockIdx.x, b = blockIdx.y;
  const int tid = threadIdx.x, lane = tid&63, hh = tid>>6;   // hh = head 0..7
  const int m0 = b*4096 + ck*64;
  u16* XT = (u16*)(lds + 17664 + hh*9232);  // [64][72] per head: [p][t]; later Y/g [t][p]
  // (a) staging
  for (int i=tid; i<32*72; i+=512){
    int n = i/72, r = i - n*72;
    if (r < 67){
      int l = ck*64 - 3 + r;
      rawBC[r*33+n] = (l>=0) ? bf2f(xT[(size_t)(512+n)*32768 + (size_t)b*4096 + l]) : 0.f;
    }
  }
  {
    int t = lane;
    float dr = dtr[(size_t)(m0+t)*8 + hh] + dt_bias[hh];
    float dt = (dr > 20.f) ? dr : log1pf(__expf(dr));
    float Ah = -__expf(A_log[hh]);
    float v = dt*Ah;
    #pragma unroll
    for (int off=1; off<64; off<<=1){ float p = __shfl_up(v, off); if (lane >= off) v += p; }
    dth[hh*68 + t] = dt;
    scs[hh*68 + t] = v;
  }
  {
    const int c = hh*64 + lane;
    const float w0=conv_w[c*4], w1=conv_w[c*4+1], w2=conv_w[c*4+2], w3=conv_w[c*4+3];
    const float cb = conv_b[c];
    const u16* xcol = xT + (size_t)c*32768 + (size_t)b*4096 + ck*64;
    u16x8 wv[9]; u16x8 zer = {};
    wv[0] = (ck>0) ? *(const u16x8*)(xcol - 8) : zer;
    #pragma unroll
    for (int j=0;j<8;++j) wv[j+1] = *(const u16x8*)(xcol + j*8);
    #pragma unroll
    for (int t8=0; t8<8; ++t8){
      u16x8 o;
      #pragma unroll
      for (int j=0;j<8;++j){
        const int t = t8*8+j;
        float x0 = bf2f(wv[(t+5)>>3][(t+5)&7]);
        float x1 = bf2f(wv[(t+6)>>3][(t+6)&7]);
        float x2 = bf2f(wv[(t+7)>>3][(t+7)&7]);
        float x3 = bf2f(wv[(t+8)>>3][(t+8)&7]);
        o[j] = f2bf(siluf(cb + w0*x0 + w1*x1 + w2*x2 + w3*x3));
      }
      *(u16x8*)&XT[lane*72 + t8*8] = o;
    }
  }
  __syncthreads();
  // (b) Bc/Cc build (unpadded [64][16])
  for (int i=tid; i<64*32; i+=512){
    int s2 = i>>5, n = i&31;
    int c = 512 + n;
    float a = conv_b[c] + conv_w[c*4+0]*rawBC[s2*33+n] + conv_w[c*4+1]*rawBC[(s2+1)*33+n]
            + conv_w[c*4+2]*rawBC[(s2+2)*33+n] + conv_w[c*4+3]*rawBC[(s2+3)*33+n];
    u16 v = f2bf(siluf(a));
    if (n < 16) Bc[s2*16 + n] = v; else Cc[s2*16 + (n-16)] = v;
  }
  __syncthreads();
  // (c) G = Cc @ Bc^T (10 causal fragments across 8 waves)
  const int fr = lane&15, g = lane>>4;
  #define GFRAG(TI,SJ) { \
    short8 ca = {}, bb = {}; \
    if (g < 2){ ca = *(short8*)&Cc[((TI)*16+fr)*16 + g*8]; bb = *(short8*)&Bc[((SJ)*16+fr)*16 + g*8]; } \
    f32x4 d = {}; \
    d = __builtin_amdgcn_mfma_f32_16x16x32_bf16(ca,bb,d,0,0,0); \
    G[((TI)*16 + g*4 + 0)*72 + (SJ)*16 + fr] = f2bf(d[0]); \
    G[((TI)*16 + g*4 + 1)*72 + (SJ)*16 + fr] = f2bf(d[1]); \
    G[((TI)*16 + g*4 + 2)*72 + (SJ)*16 + fr] = f2bf(d[2]); \
    G[((TI)*16 + g*4 + 3)*72 + (SJ)*16 + fr] = f2bf(d[3]); }
  if      (hh==0){ GFRAG(0,0) GFRAG(3,2) }
  else if (hh==1){ GFRAG(1,0) GFRAG(3,3) }
  else if (hh==2){ GFRAG(1,1) }
  else if (hh==3){ GFRAG(2,0) }
  else if (hh==4){ GFRAG(2,1) }
  else if (hh==5){ GFRAG(2,2) }
  else if (hh==6){ GFRAG(3,0) }
  else           { GFRAG(3,1) }
  #undef GFRAG
  __syncthreads();
  // (d) per-head output
  f32x4 acc[4][4] = {};
  {
    size_t hsbase = ((size_t)((b*8+hh)*64 + ck))*64*16;
    short8 h0f[4];
    #pragma unroll
    for (int pj=0; pj<4; ++pj){
      short8 hf = {};
      if (g < 2){
        int p = pj*16 + fr;
        f32x4 lo = *(const f32x4*)&hs[hsbase + p*16 + g*8];
        f32x4 hi = *(const f32x4*)&hs[hsbase + p*16 + g*8 + 4];
        #pragma unroll
        for (int kk=0; kk<4; ++kk){ hf[kk] = (short)f2bf(lo[kk]); hf[kk+4] = (short)f2bf(hi[kk]); }
      }
      h0f[pj] = hf;
    }
    #pragma unroll
    for (int ti=0; ti<4; ++ti){
      short8 ca = {};
      if (g < 2) ca = *(short8*)&Cc[(ti*16+fr)*16 + g*8];
      #pragma unroll
      for (int pj=0; pj<4; ++pj)
        acc[ti][pj] = __builtin_amdgcn_mfma_f32_16x16x32_bf16(ca, h0f[pj], acc[ti][pj], 0,0,0);
    }
  }
  #pragma unroll
  for (int ti=0; ti<4; ++ti)
    #pragma unroll
    for (int i=0; i<4; ++i){
      float pt = __expf(scs[hh*68 + ti*16 + g*4 + i]);
      #pragma unroll
      for (int pj=0; pj<4; ++pj) acc[ti][pj][i] *= pt;
    }
  // intra: masked M @ Xc
  #pragma unroll
  for (int ks=0; ks<2; ++ks){
    short8 xf[4];
    #pragma unroll
    for (int pj=0; pj<4; ++pj) xf[pj] = *(short8*)&XT[(pj*16+fr)*72 + ks*32 + g*8];
    #pragma unroll
    for (int ti=0; ti<4; ++ti){
      if (ks*32 > ti*16+15) continue;
      int t = ti*16 + fr;
      float sct = scs[hh*68 + t];
      f32x4 sc0 = *(f32x4*)&scs[hh*68 + ks*32 + g*8];
      f32x4 sc1 = *(f32x4*)&scs[hh*68 + ks*32 + g*8 + 4];
      f32x4 dt0 = *(f32x4*)&dth[hh*68 + ks*32 + g*8];
      f32x4 dt1 = *(f32x4*)&dth[hh*68 + ks*32 + g*8 + 4];
      u16x8 g8 = *(u16x8*)&G[t*72 + ks*32 + g*8];
      short8 mf;
      #pragma unroll
      for (int kk=0; kk<8; ++kk){
        int s2 = ks*32 + g*8 + kk;
        float sv = (kk<4) ? sc0[kk] : sc1[kk-4];
        float dv = (kk<4) ? dt0[kk] : dt1[kk-4];
        float m = (s2 <= t) ? bf2f(g8[kk]) * __expf(sct - sv) * dv : 0.f;
        mf[kk] = (short)f2bf(m);
      }
      #pragma unroll
      for (int pj=0; pj<4; ++pj)
        acc[ti][pj] = __builtin_amdgcn_mfma_f32_16x16x32_bf16(mf, xf[pj], acc[ti][pj], 0,0,0);
    }
  }
  // + D*x (all reads of XT x-values before Y overwrite)
  {
    const float Dh = Dp[hh];
    #pragma unroll
    for (int ti=0; ti<4; ++ti)
      #pragma unroll
      for (int pj=0; pj<4; ++pj){
        int p = pj*16 + fr;
        u16x4 xv = *(u16x4*)&XT[p*72 + ti*16 + g*4];
        #pragma unroll
        for (int i=0; i<4; ++i) acc[ti][pj][i] += Dh * bf2f(xv[i]);
      }
  }
  // write Y [t][p] into own region
  #pragma unroll
  for (int ti=0; ti<4; ++ti)
    #pragma unroll
    for (int pj=0; pj<4; ++pj)
      #pragma unroll
      for (int i=0; i<4; ++i)
        XT[(ti*16 + g*4 + i)*72 + pj*16 + fr] = f2bf(acc[ti][pj][i]);
  __syncthreads();
  // (f) fused gate + RMSNorm: thread (r = tid>>3, q = tid&7) owns row r, head q
  {
    const int r = tid>>3;
    const int q = tid&7;
    u16* Yq = (u16*)(lds + 17664 + q*9232);
    const size_t mrow = (size_t)m0 + r;
    float ssum = 0.f;
    #pragma unroll
    for (int jv=0; jv<8; ++jv){
      u16x8 yv = *(u16x8*)&Yq[r*72 + jv*8];
      u16x8 gv;
      #pragma unroll
      for (int j=0; j<8; ++j){
        int p = q*64 + jv*8 + j;
        float zf = bf2f(zxT[(size_t)p*32768 + mrow]);
        float gg = bf2f(yv[j]) * (zf/(1.f + __expf(-zf)));
        ssum += gg*gg;
        gv[j] = f2bf(gg);
      }
      *(u16x8*)&Yq[r*72 + jv*8] = gv;
    }
    ssum += __shfl_xor(ssum, 1);
    ssum += __shfl_xor(ssum, 2);
    ssum += __shfl_xor(ssum, 4);
    float rs = rsqrtf(ssum*(1.f/512.f) + 1e-5f);
    #pragma unroll
    for (int jv=0; jv<8; ++jv){
      u16x8 gv = *(u16x8*)&Yq[r*72 + jv*8];
      u16x8 o;
      #pragma unroll
      for (int j=0; j<8; ++j){
        int p = q*64 + jv*8 + j;
        o[j] = f2bf(bf2f(gv[j]) * rs * rms_w[p]);
      }
      *(u16x8*)&ynb[mrow*512 + q*64 + jv*8] = o;
    }
  }
}

// ---------------- K8: GEMM2 128x128, XCD-swizzled, transposed store + residual ----------------
__global__ __launch_bounds__(256) void k8_gemm2(const u16* __restrict__ A, const u16* __restrict__ W,
                                                const float* __restrict__ xres, float* __restrict__ out){
  __shared__ float smem[4*64*65];
  u16* sA = (u16*)smem;
  u16* sW = ((u16*)smem) + 128*40;
  const int tid = threadIdx.x, lane = tid&63, wave = tid>>6;
  const int s = blockIdx.x;
  const int kx = s & 7;
  const int idx = s >> 3;          // 0..63
  const int xn = idx & 1;
  const int ym = (idx>>1)*8 + kx;  // 0..255
  const size_t m0 = (size_t)ym*128;
  const int n0 = xn*128;
  const int wm = (wave>>1)*64, wn = (wave&1)*64;
  f32x4 acc[4][4] = {};
  const int fr = lane&15, kc = (lane>>4)*8;
  for (int k0=0; k0<512; k0+=32){
    #pragma unroll
    for (int j=0; j<2; ++j){
      int ch = j*256 + tid, r = ch>>2, co = (ch&3)*8;
      *(u16x8*)&sA[r*40+co] = *(const u16x8*)&A[(m0+r)*512 + k0 + co];
      *(u16x8*)&sW[r*40+co] = *(const u16x8*)&W[(size_t)(n0+r)*512 + k0 + co];
    }
    __syncthreads();
    short8 af[4], bf4[4];
    #pragma unroll
    for (int fm=0; fm<4; ++fm) af[fm]  = *(short8*)&sA[(wm+fm*16+fr)*40 + kc];
    #pragma unroll
    for (int fn=0; fn<4; ++fn) bf4[fn] = *(short8*)&sW[(wn+fn*16+fr)*40 + kc];
    #pragma unroll
    for (int fm=0; fm<4; ++fm)
      #pragma unroll
      for (int fn=0; fn<4; ++fn)
        acc[fm][fn] = __builtin_amdgcn_mfma_f32_16x16x32_bf16(af[fm],bf4[fn],acc[fm][fn],0,0,0);
    __syncthreads();
  }
  float* T = smem + wave*(64*65);
  #pragma unroll
  for (int fm=0; fm<4; ++fm)
    #pragma unroll
    for (int fn=0; fn<4; ++fn){
      int rr = fm*16 + ((lane>>4)<<2);
      int cc = fn*16 + (lane&15);
      #pragma unroll
      for (int i=0; i<4; ++i) T[(rr+i)*65 + cc] = acc[fm][fn][i];
    }
  __syncthreads();
  const int bb = (int)(m0>>12);
  const int lbase = (int)(m0&4095) + wm;
  for (int cc=0; cc<64; ++cc){
    int col = n0 + wn + cc;
    size_t o = ((size_t)bb*256 + col)*4096 + lbase + lane;
    out[o] = T[lane*65 + cc] + xres[o];
  }
}

// ---------------- launcher ----------------
extern "C" void kernel_launch(void* const* d_in, const int* in_sizes, int n_in,
                              void* d_out, int out_size, void* d_ws, size_t ws_size,
                              hipStream_t stream){
  const float* x        = (const float*)d_in[0];
  const float* ln_w     = (const float*)d_in[1];
  const float* ln_b     = (const float*)d_in[2];
  const float* in_proj  = (const float*)d_in[3];
  const float* conv_w   = (const float*)d_in[4];
  const float* conv_b   = (const float*)d_in[5];
  const float* dt_bias  = (const float*)d_in[6];
  const float* A_log    = (const float*)d_in[7];
  const float* Dp       = (const float*)d_in[8];
  const float* rms_w    = (const float*)d_in[9];
  const float* out_proj = (const float*)d_in[10];
  float* out = (float*)d_out;

  char* ws = (char*)d_ws;
  const size_t o_w1   = 0;            // 1152*256*2 = 589824
  const size_t o_w2   = 589824;       // 262144 -> 851968
  const size_t o_xn   = 851968;       // 16777216 -> 17629184
  const size_t o_zxT  = 17629184;     // 1056*32768*2 = 69206016 -> 86835200
  const size_t o_dtr  = 86835200;     // 1048576 -> 87883776
  const size_t o_hend = 87883776;     // 16777216 -> 104660992
  const size_t o_hs   = 104660992;    // 16777216 -> 121438208
  const size_t o_ap   = 121438208;    // 16384 -> 121454592
  const size_t o_ynb  = 121454592;    // 33554432 -> 155009024
  const size_t NEED   = 155009024;
  if (ws_size < NEED) return;

  u16*   w1b  = (u16*)(ws + o_w1);
  u16*   w2b  = (u16*)(ws + o_w2);
  u16*   xnb  = (u16*)(ws + o_xn);
  u16*   zxT  = (u16*)(ws + o_zxT);
  u16*   xTb  = zxT + (size_t)512*32768;     // xBC view (cols 512..1055)
  float* dtr  = (float*)(ws + o_dtr);
  float* hend = (float*)(ws + o_hend);
  float* hsb  = (float*)(ws + o_hs);
  float* ap   = (float*)(ws + o_ap);
  u16*   ynb  = (u16*)(ws + o_ynb);

  k0_wprep<<<1664, 256, 0, stream>>>(in_proj, out_proj, w1b, w2b);
  k1_ln<<<dim3(128, 8), 256, 0, stream>>>(x, ln_w, ln_b, in_proj, xnb, dtr);
  k2_gemm1<<<2304, 256, 0, stream>>>(xnb, w1b, zxT);
  kU<<<dim3(64, 8, 2), 256, 0, stream>>>(xTb, dtr, conv_w, conv_b, dt_bias, A_log, hend, ap);
  k5_phase2<<<64, 256, 0, stream>>>(hend, ap, hsb);
  kYR<<<dim3(64, 8), 512, 0, stream>>>(xTb, zxT, dtr, conv_w, conv_b, dt_bias, A_log, Dp, rms_w, hsb, ynb);
  k8_gemm2<<<512, 256, 0, stream>>>(ynb, w2b, x, out);
}

// Round 10
// 279.623 us; speedup vs baseline: 1.0857x; 1.0857x over previous
//
#include <hip/hip_runtime.h>
#include <cstdint>

typedef unsigned short u16;
typedef unsigned int u32;
typedef u16 u16x8 __attribute__((ext_vector_type(8)));
typedef u16 u16x4 __attribute__((ext_vector_type(4)));
typedef short short8 __attribute__((ext_vector_type(8)));
typedef float f32x4 __attribute__((ext_vector_type(4)));

__device__ __forceinline__ float bf2f(u16 u){ return __uint_as_float(((u32)u)<<16); }
__device__ __forceinline__ u16 f2bf(float f){
  u32 x = __float_as_uint(f);
  return (u16)((x + 0x7fffu + ((x>>16)&1u)) >> 16);
}
__device__ __forceinline__ float siluf(float v){ return v/(1.f + __expf(-v)); }

// B=8, L=4096, C=256, D_INNER=512, CONV_DIM=544, NH=8, HD=64, DS=16, chunk Lc=64
// z: row-major [32768][512] bf16 (gate-friendly). xT: [544][32768] bf16 (scan-friendly).
// hend/hs: bf16 (halved h-state round-trip traffic).

// ---------------- K0: weights -> bf16 ----------------
__global__ __launch_bounds__(256) void k0_wprep(const float* __restrict__ w1,
                                                const float* __restrict__ w2,
                                                u16* __restrict__ w1b, u16* __restrict__ w2b){
  u32 idx = blockIdx.x*256u + threadIdx.x;
  const u32 W1N = 1152u*256u;
  const u32 W2N = 256u*512u;
  if (idx < W1N){
    u32 n = idx >> 8;
    w1b[idx] = (n < 1064u) ? f2bf(w1[idx]) : (u16)0;
  } else if (idx < W1N + W2N){
    u32 j = idx - W1N;
    w2b[j] = f2bf(w2[j]);
  }
}

// ---------------- K1: transpose + LayerNorm + dt(f32) ----------------
__global__ __launch_bounds__(256) void k1_ln(const float* __restrict__ x,
                                             const float* __restrict__ ln_w, const float* __restrict__ ln_b,
                                             const float* __restrict__ w1,
                                             u16* __restrict__ xnb, float* __restrict__ dtr){
  __shared__ float tile[256][33];
  __shared__ float mu_s[32], rs_s[32];
  const int b  = blockIdx.y;
  const int l0 = blockIdx.x*32;
  const int tid = threadIdx.x;
  const size_t xbase = (size_t)b*256*4096;
  const int cl = tid>>5;
  const int ll = tid&31;
  for (int cc=0; cc<256; cc+=8){
    int c = cc + cl;
    tile[c][ll] = x[xbase + (size_t)c*4096 + l0 + ll];
  }
  __syncthreads();
  const int lane = tid&63, wave = tid>>6;
  const int lidx = wave*8 + (lane&7);
  const int c0 = (lane>>3)*32;
  float s=0.f, ss=0.f;
  for (int c=c0; c<c0+32; ++c){ float v = tile[c][lidx]; s += v; ss += v*v; }
  for (int off=8; off<64; off<<=1){ s += __shfl_xor(s, off); ss += __shfl_xor(ss, off); }
  float mu = s*(1.f/256.f);
  float var = ss*(1.f/256.f) - mu*mu;
  float rs = rsqrtf(var + 1e-5f);
  if ((lane>>3)==0){ mu_s[lidx]=mu; rs_s[lidx]=rs; }
  __syncthreads();
  {
    const int c = tid;
    const float lw = ln_w[c], lb = ln_b[c];
    for (int l=0; l<32; ++l){
      float v = (tile[c][l]-mu_s[l])*rs_s[l]*lw + lb;
      xnb[((size_t)b*4096 + l0 + l)*256 + c] = f2bf(v);
    }
  }
  {
    const int r = tid>>3, j = tid&7;
    const float* wr = w1 + (size_t)(1056+j)*256;
    const float mur = mu_s[r], rsr = rs_s[r];
    float acc = 0.f;
    for (int c=0; c<256; ++c){
      float v = (tile[c][r]-mur)*rsr*ln_w[c] + ln_b[c];
      acc += v*wr[c];
    }
    dtr[((size_t)b*4096 + l0 + r)*8 + j] = acc;
  }
}

// ---------------- K2: GEMM1 128x128, XCD-swizzled, z row-major / x transposed ----------------
__global__ __launch_bounds__(256) void k2_gemm1(const u16* __restrict__ A, const u16* __restrict__ W,
                                                u16* __restrict__ zb, u16* __restrict__ xT){
  __shared__ u16 sA[128*40];
  __shared__ u16 sW[128*40];
  const int tid = threadIdx.x, lane = tid&63, wave = tid>>6;
  const int s = blockIdx.x;
  const int kx = s & 7;
  const int idx = s >> 3;          // 0..287
  const int xn = idx % 9;
  const int ym = (idx/9)*8 + kx;   // 0..255
  const size_t m0 = (size_t)ym*128;
  const int n0 = xn*128;
  const int wm = (wave>>1)*64, wn = (wave&1)*64;
  f32x4 acc[4][4] = {};
  const int fr = lane&15, kc = (lane>>4)*8;
  for (int k0=0; k0<256; k0+=32){
    #pragma unroll
    for (int j=0; j<2; ++j){
      int ch = j*256 + tid, r = ch>>2, co = (ch&3)*8;
      *(u16x8*)&sA[r*40+co] = *(const u16x8*)&A[(m0+r)*256 + k0 + co];
      *(u16x8*)&sW[r*40+co] = *(const u16x8*)&W[(size_t)(n0+r)*256 + k0 + co];
    }
    __syncthreads();
    short8 af[4], bf4[4];
    #pragma unroll
    for (int fm=0; fm<4; ++fm) af[fm]  = *(short8*)&sA[(wm+fm*16+fr)*40 + kc];
    #pragma unroll
    for (int fn=0; fn<4; ++fn) bf4[fn] = *(short8*)&sW[(wn+fn*16+fr)*40 + kc];
    #pragma unroll
    for (int fm=0; fm<4; ++fm)
      #pragma unroll
      for (int fn=0; fn<4; ++fn)
        acc[fm][fn] = __builtin_amdgcn_mfma_f32_16x16x32_bf16(af[fm],bf4[fn],acc[fm][fn],0,0,0);
    __syncthreads();
  }
  #pragma unroll
  for (int fm=0; fm<4; ++fm)
    #pragma unroll
    for (int fn=0; fn<4; ++fn){
      int rb = wm + fm*16 + ((lane>>4)<<2);
      int col = n0 + wn + fn*16 + (lane&15);
      size_t m = m0 + rb;
      if (col < 512){
        #pragma unroll
        for (int i=0; i<4; ++i) zb[(m+i)*512 + col] = f2bf(acc[fm][fn][i]);
      } else if (col < 1056){
        u16x4 o;
        #pragma unroll
        for (int i=0; i<4; ++i) o[i] = f2bf(acc[fm][fn][i]);
        *(u16x4*)&xT[(size_t)(col-512)*32768 + m] = o;
      }
    }
}

// ---------------- kU: chunk-end states via MFMA (hend bf16) ----------------
__global__ __launch_bounds__(256,3) void kU(const u16* __restrict__ xT, const float* __restrict__ dtr,
                                          const float* __restrict__ conv_w, const float* __restrict__ conv_b,
                                          const float* __restrict__ dt_bias, const float* __restrict__ A_log,
                                          u16* __restrict__ hend, float* __restrict__ aprod){
  __shared__ char lds[44816];
  float* rawB = (float*)(lds + 0);        // [67][17] f32
  u16*   BcT  = (u16*)(lds + 4560);       // [16][72] bf16
  float* wl   = (float*)(lds + 6864);     // [4][64] f32
  const int ck = blockIdx.x, b = blockIdx.y, half = blockIdx.z;
  const int tid = threadIdx.x, lane = tid&63, hh = tid>>6;
  const int h = half*4 + hh;
  const int m0 = b*4096 + ck*64;
  u16* XW = (u16*)(lds + 7888 + hh*9232); // [64][72] per head
  for (int i=tid; i<16*72; i+=256){
    int n = i/72, r = i - n*72;
    if (r < 67){
      int l = ck*64 - 3 + r;
      rawB[r*17+n] = (l>=0) ? bf2f(xT[(size_t)(512+n)*32768 + (size_t)b*4096 + l]) : 0.f;
    }
  }
  {
    int t = lane;
    float dr = dtr[(size_t)(m0+t)*8 + h] + dt_bias[h];
    float dt = (dr > 20.f) ? dr : log1pf(__expf(dr));
    float Ah = -__expf(A_log[h]);
    float v = dt*Ah;
    #pragma unroll
    for (int off=1; off<64; off<<=1){ float p = __shfl_up(v, off); if (lane >= off) v += p; }
    float scT = __shfl(v, 63);
    wl[hh*64 + t] = dt * __expf(scT - v);
    if (lane==0) aprod[(b*8+h)*64 + ck] = __expf(scT);
  }
  __syncthreads();
  for (int i=tid; i<16*64; i+=256){
    int n = i>>6, s2 = i&63;
    int c = 512+n;
    float a = conv_b[c] + conv_w[c*4+0]*rawB[s2*17+n] + conv_w[c*4+1]*rawB[(s2+1)*17+n]
            + conv_w[c*4+2]*rawB[(s2+2)*17+n] + conv_w[c*4+3]*rawB[(s2+3)*17+n];
    BcT[n*72 + s2] = f2bf(siluf(a));
  }
  {
    const int c = h*64 + lane;
    const float w0=conv_w[c*4], w1=conv_w[c*4+1], w2=conv_w[c*4+2], w3=conv_w[c*4+3];
    const float cb = conv_b[c];
    const u16* xcol = xT + (size_t)c*32768 + (size_t)b*4096 + ck*64;
    u16x8 wv[9]; u16x8 zer = {};
    wv[0] = (ck>0) ? *(const u16x8*)(xcol - 8) : zer;
    #pragma unroll
    for (int j=0;j<8;++j) wv[j+1] = *(const u16x8*)(xcol + j*8);
    #pragma unroll
    for (int t8=0; t8<8; ++t8){
      u16x8 o;
      #pragma unroll
      for (int j=0;j<8;++j){
        const int t = t8*8+j;
        float x0 = bf2f(wv[(t+5)>>3][(t+5)&7]);
        float x1 = bf2f(wv[(t+6)>>3][(t+6)&7]);
        float x2 = bf2f(wv[(t+7)>>3][(t+7)&7]);
        float x3 = bf2f(wv[(t+8)>>3][(t+8)&7]);
        o[j] = f2bf(siluf(cb + w0*x0 + w1*x1 + w2*x2 + w3*x3) * wl[hh*64 + t]);
      }
      *(u16x8*)&XW[lane*72 + t8*8] = o;
    }
  }
  __syncthreads();
  const int fr = lane&15, g = lane>>4;
  f32x4 acc4[4] = {};
  #pragma unroll
  for (int ks=0; ks<2; ++ks){
    short8 bfr = *(short8*)&BcT[fr*72 + ks*32 + g*8];
    #pragma unroll
    for (int ti=0; ti<4; ++ti){
      short8 afr = *(short8*)&XW[(ti*16+fr)*72 + ks*32 + g*8];
      acc4[ti] = __builtin_amdgcn_mfma_f32_16x16x32_bf16(afr, bfr, acc4[ti], 0,0,0);
    }
  }
  size_t hb = ((size_t)((b*8+h)*64 + ck))*64;
  #pragma unroll
  for (int ti=0; ti<4; ++ti)
    #pragma unroll
    for (int i=0; i<4; ++i){
      int p = ti*16 + g*4 + i;
      hend[(hb + p)*16 + fr] = f2bf(acc4[ti][i]);
    }
}

// ---------------- K5: inter-chunk recurrence (4 waves, bf16 in/out, f32 accum) ----------------
__global__ __launch_bounds__(256) void k5_phase2(const u16* __restrict__ hend, const float* __restrict__ aprod,
                                                 u16* __restrict__ hs){
  const int bh = blockIdx.x;
  const int w = threadIdx.x>>6, lane = threadIdx.x&63;
  const int n0 = w*4;
  float hr[4] = {0.f,0.f,0.f,0.f};
  for (int ck=0; ck<64; ++ck){
    size_t base = (((size_t)bh*64 + ck)*64 + lane)*16 + n0;
    float a = aprod[bh*64 + ck];
    u16x4 o;
    #pragma unroll
    for (int j=0;j<4;++j) o[j] = f2bf(hr[j]);
    *(u16x4*)&hs[base] = o;
    u16x4 he = *(const u16x4*)&hend[base];
    #pragma unroll
    for (int j=0;j<4;++j) hr[j] = a*hr[j] + bf2f(he[j]);
  }
}

// ---------------- kY: chunk outputs via MFMA (hs bf16 direct-load) ----------------
__global__ __launch_bounds__(256,3) void kY(const u16* __restrict__ xT, const float* __restrict__ dtr,
                                          const float* __restrict__ conv_w, const float* __restrict__ conv_b,
                                          const float* __restrict__ dt_bias, const float* __restrict__ A_log,
                                          const float* __restrict__ Dp, const u16* __restrict__ hs,
                                          u16* __restrict__ ybh){
  __shared__ char lds[52416];
  u16*   G     = (u16*)(lds + 0);       // [64][72] bf16 (union rawBC)
  float* rawBC = (float*)(lds + 0);     // [67][33] f32
  u16*   Cc    = (u16*)(lds + 9216);    // [64][16] bf16 (unpadded)
  u16*   Bc    = (u16*)(lds + 11264);   // [64][16]
  float* scs   = (float*)(lds + 13312); // [4][68]
  float* dth   = (float*)(lds + 14400); // [4][68]
  const int ck = blockIdx.x, b = blockIdx.y, half = blockIdx.z;
  const int tid = threadIdx.x, lane = tid&63, hh = tid>>6;
  const int h = half*4 + hh;
  const int m0 = b*4096 + ck*64;
  u16* XT = (u16*)(lds + 15488 + hh*9232);  // [64][72] per head: [p][t]; later Y [t][p]
  for (int i=tid; i<32*72; i+=256){
    int n = i/72, r = i - n*72;
    if (r < 67){
      int l = ck*64 - 3 + r;
      rawBC[r*33+n] = (l>=0) ? bf2f(xT[(size_t)(512+n)*32768 + (size_t)b*4096 + l]) : 0.f;
    }
  }
  {
    int t = lane;
    float dr = dtr[(size_t)(m0+t)*8 + h] + dt_bias[h];
    float dt = (dr > 20.f) ? dr : log1pf(__expf(dr));
    float Ah = -__expf(A_log[h]);
    float v = dt*Ah;
    #pragma unroll
    for (int off=1; off<64; off<<=1){ float p = __shfl_up(v, off); if (lane >= off) v += p; }
    dth[hh*68 + t] = dt;
    scs[hh*68 + t] = v;
  }
  {
    const int c = h*64 + lane;
    const float w0=conv_w[c*4], w1=conv_w[c*4+1], w2=conv_w[c*4+2], w3=conv_w[c*4+3];
    const float cb = conv_b[c];
    const u16* xcol = xT + (size_t)c*32768 + (size_t)b*4096 + ck*64;
    u16x8 wv[9]; u16x8 zer = {};
    wv[0] = (ck>0) ? *(const u16x8*)(xcol - 8) : zer;
    #pragma unroll
    for (int j=0;j<8;++j) wv[j+1] = *(const u16x8*)(xcol + j*8);
    #pragma unroll
    for (int t8=0; t8<8; ++t8){
      u16x8 o;
      #pragma unroll
      for (int j=0;j<8;++j){
        const int t = t8*8+j;
        float x0 = bf2f(wv[(t+5)>>3][(t+5)&7]);
        float x1 = bf2f(wv[(t+6)>>3][(t+6)&7]);
        float x2 = bf2f(wv[(t+7)>>3][(t+7)&7]);
        float x3 = bf2f(wv[(t+8)>>3][(t+8)&7]);
        o[j] = f2bf(siluf(cb + w0*x0 + w1*x1 + w2*x2 + w3*x3));
      }
      *(u16x8*)&XT[lane*72 + t8*8] = o;
    }
  }
  __syncthreads();
  for (int i=tid; i<64*32; i+=256){
    int s2 = i>>5, n = i&31;
    int c = 512 + n;
    float a = conv_b[c] + conv_w[c*4+0]*rawBC[s2*33+n] + conv_w[c*4+1]*rawBC[(s2+1)*33+n]
            + conv_w[c*4+2]*rawBC[(s2+2)*33+n] + conv_w[c*4+3]*rawBC[(s2+3)*33+n];
    u16 v = f2bf(siluf(a));
    if (n < 16) Bc[s2*16 + n] = v; else Cc[s2*16 + (n-16)] = v;
  }
  __syncthreads();
  const int fr = lane&15, g = lane>>4;
  #define GFRAG(TI,SJ) { \
    short8 ca = {}, bb = {}; \
    if (g < 2){ ca = *(short8*)&Cc[((TI)*16+fr)*16 + g*8]; bb = *(short8*)&Bc[((SJ)*16+fr)*16 + g*8]; } \
    f32x4 d = {}; \
    d = __builtin_amdgcn_mfma_f32_16x16x32_bf16(ca,bb,d,0,0,0); \
    G[((TI)*16 + g*4 + 0)*72 + (SJ)*16 + fr] = f2bf(d[0]); \
    G[((TI)*16 + g*4 + 1)*72 + (SJ)*16 + fr] = f2bf(d[1]); \
    G[((TI)*16 + g*4 + 2)*72 + (SJ)*16 + fr] = f2bf(d[2]); \
    G[((TI)*16 + g*4 + 3)*72 + (SJ)*16 + fr] = f2bf(d[3]); }
  if      (hh==0){ GFRAG(0,0) GFRAG(2,1) GFRAG(3,2) }
  else if (hh==1){ GFRAG(1,0) GFRAG(2,2) GFRAG(3,3) }
  else if (hh==2){ GFRAG(1,1) GFRAG(3,0) }
  else           { GFRAG(2,0) GFRAG(3,1) }
  #undef GFRAG
  __syncthreads();
  f32x4 acc[4][4] = {};
  {
    size_t hsbase = ((size_t)((b*8+h)*64 + ck))*64*16;
    short8 h0f[4];
    #pragma unroll
    for (int pj=0; pj<4; ++pj){
      short8 hf = {};
      if (g < 2){
        int p = pj*16 + fr;
        hf = *(short8*)&hs[hsbase + p*16 + g*8];
      }
      h0f[pj] = hf;
    }
    #pragma unroll
    for (int ti=0; ti<4; ++ti){
      short8 ca = {};
      if (g < 2) ca = *(short8*)&Cc[(ti*16+fr)*16 + g*8];
      #pragma unroll
      for (int pj=0; pj<4; ++pj)
        acc[ti][pj] = __builtin_amdgcn_mfma_f32_16x16x32_bf16(ca, h0f[pj], acc[ti][pj], 0,0,0);
    }
  }
  #pragma unroll
  for (int ti=0; ti<4; ++ti)
    #pragma unroll
    for (int i=0; i<4; ++i){
      float pt = __expf(scs[hh*68 + ti*16 + g*4 + i]);
      #pragma unroll
      for (int pj=0; pj<4; ++pj) acc[ti][pj][i] *= pt;
    }
  #pragma unroll
  for (int ks=0; ks<2; ++ks){
    short8 xf[4];
    #pragma unroll
    for (int pj=0; pj<4; ++pj) xf[pj] = *(short8*)&XT[(pj*16+fr)*72 + ks*32 + g*8];
    #pragma unroll
    for (int ti=0; ti<4; ++ti){
      if (ks*32 > ti*16+15) continue;
      int t = ti*16 + fr;
      float sct = scs[hh*68 + t];
      f32x4 sc0 = *(f32x4*)&scs[hh*68 + ks*32 + g*8];
      f32x4 sc1 = *(f32x4*)&scs[hh*68 + ks*32 + g*8 + 4];
      f32x4 dt0 = *(f32x4*)&dth[hh*68 + ks*32 + g*8];
      f32x4 dt1 = *(f32x4*)&dth[hh*68 + ks*32 + g*8 + 4];
      u16x8 g8 = *(u16x8*)&G[t*72 + ks*32 + g*8];
      short8 mf;
      #pragma unroll
      for (int kk=0; kk<8; ++kk){
        int s2 = ks*32 + g*8 + kk;
        float sv = (kk<4) ? sc0[kk] : sc1[kk-4];
        float dv = (kk<4) ? dt0[kk] : dt1[kk-4];
        float m = (s2 <= t) ? bf2f(g8[kk]) * __expf(sct - sv) * dv : 0.f;
        mf[kk] = (short)f2bf(m);
      }
      #pragma unroll
      for (int pj=0; pj<4; ++pj)
        acc[ti][pj] = __builtin_amdgcn_mfma_f32_16x16x32_bf16(mf, xf[pj], acc[ti][pj], 0,0,0);
    }
  }
  {
    const float Dh = Dp[h];
    #pragma unroll
    for (int ti=0; ti<4; ++ti)
      #pragma unroll
      for (int pj=0; pj<4; ++pj){
        int p = pj*16 + fr;
        u16x4 xv = *(u16x4*)&XT[p*72 + ti*16 + g*4];
        #pragma unroll
        for (int i=0; i<4; ++i) acc[ti][pj][i] += Dh * bf2f(xv[i]);
      }
  }
  #pragma unroll
  for (int ti=0; ti<4; ++ti)
    #pragma unroll
    for (int pj=0; pj<4; ++pj)
      #pragma unroll
      for (int i=0; i<4; ++i)
        XT[(ti*16 + g*4 + i)*72 + pj*16 + fr] = f2bf(acc[ti][pj][i]);
  __syncthreads();
  {
    const int hl = lane>>4;
    const u16* R = (const u16*)(lds + 15488 + hl*9232);
    #pragma unroll
    for (int tt=0; tt<16; ++tt){
      int t = hh*16 + tt;
      u16x4 v = *(const u16x4*)&R[t*72 + (lane&15)*4];
      *(u16x4*)&ybh[(size_t)(m0+t)*512 + half*256 + lane*4] = v;
    }
  }
}

// ---------------- K7: gate + RMSNorm (row-major coalesced) ----------------
__global__ __launch_bounds__(256) void k7_rms(const u16* __restrict__ y, const u16* __restrict__ zb,
                                              const float* __restrict__ rms_w, u16* __restrict__ ynb){
  const int m = blockIdx.x*4 + (threadIdx.x>>6);
  const int lane = threadIdx.x&63;
  const size_t base = (size_t)m*512 + lane*8;
  u16x8 yv = *(const u16x8*)&y[base];
  u16x8 zv = *(const u16x8*)&zb[base];
  float g[8];
  float ssum = 0.f;
  #pragma unroll
  for (int j=0;j<8;++j){
    float zf = bf2f(zv[j]);
    float sig = 1.f/(1.f + __expf(-zf));
    g[j] = bf2f(yv[j]) * (zf*sig);
    ssum += g[j]*g[j];
  }
  for (int off=1; off<64; off<<=1) ssum += __shfl_xor(ssum, off);
  float rs = rsqrtf(ssum*(1.f/512.f) + 1e-5f);
  u16x8 o;
  #pragma unroll
  for (int j=0;j<8;++j) o[j] = f2bf(g[j]*rs*rms_w[lane*8+j]);
  *(u16x8*)&ynb[base] = o;
}

// ---------------- K8: GEMM2 128x128, XCD-swizzled, transposed store + residual ----------------
__global__ __launch_bounds__(256) void k8_gemm2(const u16* __restrict__ A, const u16* __restrict__ W,
                                                const float* __restrict__ xres, float* __restrict__ out){
  __shared__ float smem[4*64*65];
  u16* sA = (u16*)smem;
  u16* sW = ((u16*)smem) + 128*40;
  const int tid = threadIdx.x, lane = tid&63, wave = tid>>6;
  const int s = blockIdx.x;
  const int kx = s & 7;
  const int idx = s >> 3;          // 0..63
  const int xn = idx & 1;
  const int ym = (idx>>1)*8 + kx;  // 0..255
  const size_t m0 = (size_t)ym*128;
  const int n0 = xn*128;
  const int wm = (wave>>1)*64, wn = (wave&1)*64;
  f32x4 acc[4][4] = {};
  const int fr = lane&15, kc = (lane>>4)*8;
  for (int k0=0; k0<512; k0+=32){
    #pragma unroll
    for (int j=0; j<2; ++j){
      int ch = j*256 + tid, r = ch>>2, co = (ch&3)*8;
      *(u16x8*)&sA[r*40+co] = *(const u16x8*)&A[(m0+r)*512 + k0 + co];
      *(u16x8*)&sW[r*40+co] = *(const u16x8*)&W[(size_t)(n0+r)*512 + k0 + co];
    }
    __syncthreads();
    short8 af[4], bf4[4];
    #pragma unroll
    for (int fm=0; fm<4; ++fm) af[fm]  = *(short8*)&sA[(wm+fm*16+fr)*40 + kc];
    #pragma unroll
    for (int fn=0; fn<4; ++fn) bf4[fn] = *(short8*)&sW[(wn+fn*16+fr)*40 + kc];
    #pragma unroll
    for (int fm=0; fm<4; ++fm)
      #pragma unroll
      for (int fn=0; fn<4; ++fn)
        acc[fm][fn] = __builtin_amdgcn_mfma_f32_16x16x32_bf16(af[fm],bf4[fn],acc[fm][fn],0,0,0);
    __syncthreads();
  }
  float* T = smem + wave*(64*65);
  #pragma unroll
  for (int fm=0; fm<4; ++fm)
    #pragma unroll
    for (int fn=0; fn<4; ++fn){
      int rr = fm*16 + ((lane>>4)<<2);
      int cc = fn*16 + (lane&15);
      #pragma unroll
      for (int i=0; i<4; ++i) T[(rr+i)*65 + cc] = acc[fm][fn][i];
    }
  __syncthreads();
  const int bb = (int)(m0>>12);
  const int lbase = (int)(m0&4095) + wm;
  for (int cc=0; cc<64; ++cc){
    int col = n0 + wn + cc;
    size_t o = ((size_t)bb*256 + col)*4096 + lbase + lane;
    out[o] = T[lane*65 + cc] + xres[o];
  }
}

// ---------------- launcher ----------------
extern "C" void kernel_launch(void* const* d_in, const int* in_sizes, int n_in,
                              void* d_out, int out_size, void* d_ws, size_t ws_size,
                              hipStream_t stream){
  const float* x        = (const float*)d_in[0];
  const float* ln_w     = (const float*)d_in[1];
  const float* ln_b     = (const float*)d_in[2];
  const float* in_proj  = (const float*)d_in[3];
  const float* conv_w   = (const float*)d_in[4];
  const float* conv_b   = (const float*)d_in[5];
  const float* dt_bias  = (const float*)d_in[6];
  const float* A_log    = (const float*)d_in[7];
  const float* Dp       = (const float*)d_in[8];
  const float* rms_w    = (const float*)d_in[9];
  const float* out_proj = (const float*)d_in[10];
  float* out = (float*)d_out;

  char* ws = (char*)d_ws;
  const size_t o_w1   = 0;            // 589824
  const size_t o_w2   = 589824;       // 262144 -> 851968
  const size_t o_xn   = 851968;       // 16777216 -> 17629184
  const size_t o_z    = 17629184;     // 33554432 -> 51183616
  const size_t o_xT   = 51183616;     // 35651584 -> 86835200
  const size_t o_dtr  = 86835200;     // 1048576 -> 87883776
  const size_t o_hend = 87883776;     // bf16: 8388608 -> 96272384
  const size_t o_hs   = 96272384;     // bf16: 8388608 -> 104660992
  const size_t o_ap   = 104660992;    // 16384 -> 104677376
  const size_t o_ybh  = 104677376;    // 33554432 -> 138231808
  const size_t o_ynb  = 138231808;    // 33554432 -> 171786240
  const size_t NEED   = 171786240;
  if (ws_size < NEED) return;

  u16*   w1b  = (u16*)(ws + o_w1);
  u16*   w2b  = (u16*)(ws + o_w2);
  u16*   xnb  = (u16*)(ws + o_xn);
  u16*   zbuf = (u16*)(ws + o_z);
  u16*   xTb  = (u16*)(ws + o_xT);
  float* dtr  = (float*)(ws + o_dtr);
  u16*   hend = (u16*)(ws + o_hend);
  u16*   hsb  = (u16*)(ws + o_hs);
  float* ap   = (float*)(ws + o_ap);
  u16*   ybh  = (u16*)(ws + o_ybh);
  u16*   ynb  = (u16*)(ws + o_ynb);

  k0_wprep<<<1664, 256, 0, stream>>>(in_proj, out_proj, w1b, w2b);
  k1_ln<<<dim3(128, 8), 256, 0, stream>>>(x, ln_w, ln_b, in_proj, xnb, dtr);
  k2_gemm1<<<2304, 256, 0, stream>>>(xnb, w1b, zbuf, xTb);
  kU<<<dim3(64, 8, 2), 256, 0, stream>>>(xTb, dtr, conv_w, conv_b, dt_bias, A_log, hend, ap);
  k5_phase2<<<64, 256, 0, stream>>>(hend, ap, hsb);
  kY<<<dim3(64, 8, 2), 256, 0, stream>>>(xTb, dtr, conv_w, conv_b, dt_bias, A_log, Dp, hsb, ybh);
  k7_rms<<<8192, 256, 0, stream>>>(ybh, zbuf, rms_w, ynb);
  k8_gemm2<<<512, 256, 0, stream>>>(ynb, w2b, x, out);
}